// Round 5
// baseline (147.973 us; speedup 1.0000x reference)
//
#include <hip/hip_runtime.h>

#define NB 8
#define NN 4096
#define DNF 64
#define NEDGE 1048576
#define DM 64
#define FF 64

#define NBKT 512          // buckets
#define SPB 64            // segments per bucket (seg>>6 = bucket)
#define BCAP 3584         // per-bucket slot capacity (mean 2048, +34 sigma)
#define EPB 8192          // edges per bucket_scatter block
#define OVFCAP 65536

using f32x4 = __attribute__((ext_vector_type(4))) float;
using s16x8 = __attribute__((ext_vector_type(8))) short;

__device__ __forceinline__ unsigned short f2b(float f) {
    union { float f; unsigned u; } v; v.f = f;
    unsigned r = (v.u + 0x7fffu + ((v.u >> 16) & 1u)) >> 16;
    return (unsigned short)r;
}
__device__ __forceinline__ float uif(unsigned u) {
    union { unsigned u; float f; } v; v.u = u;
    return v.f;
}

// Pack W [K x Ncols] (f32 row-major) into MFMA B-fragment order (bf16)
__device__ __forceinline__ void pack_one(const float* __restrict__ W,
                                         unsigned short* __restrict__ out,
                                         int K, int Ncols, int idx) {
    int j = idx & 7;
    int lane = (idx >> 3) & 63;
    int frag = idx >> 9;
    int KS = K >> 5;
    int ks = frag % KS;
    int nt = frag / KS;
    int k = ks * 32 + ((lane >> 4) << 3) + j;
    int col = nt * 16 + (lane & 15);
    out[idx] = f2b(W[k * Ncols + col]);
}

__global__ void pack_all(const float* __restrict__ Wm1, const float* __restrict__ Wm2,
                         const float* __restrict__ Wu1, const float* __restrict__ Wu2,
                         unsigned short* __restrict__ Qw, unsigned short* __restrict__ Pw,
                         unsigned short* __restrict__ Wm2p,
                         unsigned short* __restrict__ Wu1p, unsigned short* __restrict__ Wu2p) {
    int idx = blockIdx.x * 256 + threadIdx.x;
    if (idx < 8192)        pack_one(Wm1,              Qw,   64, 128, idx);
    else if (idx < 16384)  pack_one(Wm1 + 64 * 128,   Pw,   64, 128, idx - 8192);
    else if (idx < 24576)  pack_one(Wm2,              Wm2p, 128, 64, idx - 16384);
    else if (idx < 40960)  pack_one(Wu1,              Wu1p, 128, 128, idx - 24576);
    else                   pack_one(Wu2,              Wu2p, 128, 64, idx - 40960);
}

__global__ void pack_weights(const float* __restrict__ W, unsigned short* __restrict__ out,
                             int K, int Ncols) {
    int idx = blockIdx.x * 256 + threadIdx.x;
    if (idx >= K * Ncols) return;
    pack_one(W, out, K, Ncols, idx);
}

// Q = X @ Wm1[0:64,:] + b1 (bias folded), P = X @ Wm1[64:128,:]  (bf16, 32768 x 128)
__launch_bounds__(256, 4)
__global__ void precompute_pq(const float* __restrict__ X,
                              const unsigned short* __restrict__ Qw,
                              const unsigned short* __restrict__ Pw,
                              const float* __restrict__ b1,
                              unsigned short* __restrict__ Qp,
                              unsigned short* __restrict__ Pp) {
    __shared__ unsigned short A[64][72];
    const int tid = threadIdx.x;
    const int g0 = blockIdx.x * 64;
    for (int i = 0; i < 16; ++i) {
        int idx = i * 256 + tid;
        int node = idx >> 6;
        int f = idx & 63;
        A[node][f] = f2b(X[(size_t)(g0 + node) * DNF + f]);
    }
    __syncthreads();
    const int wave = tid >> 6, lane = tid & 63;
    const int lr = lane & 15, lq = lane >> 4;
    const int arow = wave * 16 + lr;
    s16x8 a[2];
#pragma unroll
    for (int ks = 0; ks < 2; ++ks)
        a[ks] = *reinterpret_cast<const s16x8*>(&A[arow][ks * 32 + lq * 8]);
#pragma unroll
    for (int nt = 0; nt < 8; ++nt) {
        f32x4 accQ = {0.f, 0.f, 0.f, 0.f};
        f32x4 accP = {0.f, 0.f, 0.f, 0.f};
#pragma unroll
        for (int ks = 0; ks < 2; ++ks) {
            s16x8 bq = *reinterpret_cast<const s16x8*>(&Qw[(((nt << 1) + ks) * 64 + lane) * 8]);
            s16x8 bp = *reinterpret_cast<const s16x8*>(&Pw[(((nt << 1) + ks) * 64 + lane) * 8]);
            accQ = __builtin_amdgcn_mfma_f32_16x16x32_bf16(a[ks], bq, accQ, 0, 0, 0);
            accP = __builtin_amdgcn_mfma_f32_16x16x32_bf16(a[ks], bp, accP, 0, 0, 0);
        }
        int col = nt * 16 + lr;
        float bias = b1[col];
#pragma unroll
        for (int j = 0; j < 4; ++j) {
            int row = g0 + wave * 16 + lq * 4 + j;
            Qp[(size_t)row * 128 + col] = f2b(accQ[j] + bias);
            Pp[(size_t)row * 128 + col] = f2b(accP[j]);
        }
    }
}

// Pass A: block-local counting sort into 512 buckets, chunked coalesced flush.
// payload = dst[0:12) | w13[12:25) | seg_lo[25:31)
__launch_bounds__(256, 2)
__global__ void bucket_scatter(const int* __restrict__ eb, const int* __restrict__ esrc,
                               const int* __restrict__ edst, const float* __restrict__ evals,
                               unsigned* __restrict__ gcur, unsigned* __restrict__ payslot,
                               unsigned* __restrict__ ovf_cnt, unsigned* __restrict__ ovf_seg,
                               unsigned* __restrict__ ovf_pay) {
    __shared__ unsigned hist[NBKT];
    __shared__ unsigned base[NBKT];
    __shared__ unsigned curs[NBKT];
    __shared__ unsigned gbase[NBKT];
    __shared__ unsigned sorted[EPB];
    __shared__ unsigned partial[256];
    const int tid = threadIdx.x;
    const int e0 = blockIdx.x * EPB;

    for (int i = tid; i < NBKT; i += 256) hist[i] = 0;
    __syncthreads();
    // phase 1: histogram
    for (int i = 0; i < EPB / 256; ++i) {
        int e = e0 + i * 256 + tid;
        int seg = eb[e] * NN + esrc[e];
        atomicAdd(&hist[seg >> 6], 1u);
    }
    __syncthreads();
    // phase 2: exclusive scan over 512 bins (2 per thread) + global reservation
    unsigned h0 = hist[2 * tid], h1 = hist[2 * tid + 1];
    partial[tid] = h0 + h1;
    __syncthreads();
    for (int off = 1; off < 256; off <<= 1) {
        unsigned x = (tid >= off) ? partial[tid - off] : 0u;
        __syncthreads();
        partial[tid] += x;
        __syncthreads();
    }
    unsigned run = tid ? partial[tid - 1] : 0u;
    base[2 * tid] = run;        curs[2 * tid] = run;
    base[2 * tid + 1] = run + h0; curs[2 * tid + 1] = run + h0;
    gbase[2 * tid]     = h0 ? atomicAdd(&gcur[2 * tid],     h0) : 0u;
    gbase[2 * tid + 1] = h1 ? atomicAdd(&gcur[2 * tid + 1], h1) : 0u;
    __syncthreads();
    // phase 3: local scatter (edge data L2-hot from phase 1)
    for (int i = 0; i < EPB / 256; ++i) {
        int e = e0 + i * 256 + tid;
        int seg = eb[e] * NN + esrc[e];
        unsigned wq = (unsigned)fminf(evals[e] * 8192.0f + 0.5f, 8191.0f);
        unsigned pay = (unsigned)edst[e] | (wq << 12) | ((unsigned)(seg & 63) << 25);
        unsigned pos = atomicAdd(&curs[seg >> 6], 1u);
        sorted[pos] = pay;
    }
    __syncthreads();
    // phase 4: chunked flush, wave w -> buckets [w*128, (w+1)*128)
    const int wv = tid >> 6, lane = tid & 63;
    for (int j = wv * 128; j < wv * 128 + 128; ++j) {
        unsigned cnt = hist[j];
        unsigned b = base[j], gb = gbase[j];
        for (unsigned off = lane; off < cnt; off += 64) {
            unsigned v = sorted[b + off];
            unsigned g = gb + off;
            if (g < (unsigned)BCAP) {
                payslot[(size_t)j * BCAP + g] = v;
            } else {
                unsigned o = atomicAdd(ovf_cnt, 1u);
                if (o < (unsigned)OVFCAP) {
                    ovf_seg[o] = (unsigned)(j * SPB) + ((v >> 25) & 63u);
                    ovf_pay[o] = v;
                }
            }
        }
    }
}

// Pass B: one bucket (64 segments) per block. LDS counting sort by seg_lo,
// per-segment reduce s = sum w*relu(Q+P), then MFMA: gathered = (S@Wm2 + sumw*b2)/cnt.
__launch_bounds__(256, 2)
__global__ void bucket_segment(const unsigned short* __restrict__ Qp,
                               const unsigned short* __restrict__ Pp,
                               const unsigned* __restrict__ payslot,
                               const unsigned* __restrict__ gcur,
                               const unsigned* __restrict__ ovf_cnt,
                               const unsigned* __restrict__ ovf_seg,
                               const unsigned* __restrict__ ovf_pay,
                               const unsigned short* __restrict__ Wm2p,
                               const float* __restrict__ b2,
                               float* __restrict__ gathered) {
    __shared__ unsigned pays[BCAP];
    __shared__ unsigned sorted[BCAP];
    __shared__ unsigned h[SPB];
    __shared__ unsigned offs[SPB + 1];
    __shared__ unsigned cur[SPB];
    __shared__ unsigned short S[SPB][136];
    __shared__ float SW[SPB];
    __shared__ float SC[SPB];
    const int tid = threadIdx.x, wv = tid >> 6, lane = tid & 63;
    const int bkt = blockIdx.x;
    const int rowbase = (bkt >> 6) << 12;          // batch * NN
    const unsigned cnt_g = min(gcur[bkt], (unsigned)BCAP);
    const unsigned novf = ovf_cnt[0];

    if (tid < SPB) h[tid] = 0;
    __syncthreads();
    for (unsigned i = tid; i < cnt_g; i += 256) {
        unsigned v = payslot[(size_t)bkt * BCAP + i];
        pays[i] = v;
        atomicAdd(&h[(v >> 25) & 63u], 1u);
    }
    __syncthreads();
    if (tid < 64) {                                 // wave-0 inclusive scan of 64 bins
        int x = (int)h[tid];
        for (int o = 1; o < 64; o <<= 1) {
            int y = __shfl_up(x, o);
            if (tid >= o) x += y;
        }
        offs[tid + 1] = (unsigned)x;
        if (tid == 0) offs[0] = 0;
    }
    __syncthreads();
    if (tid < 64) cur[tid] = offs[tid];
    __syncthreads();
    for (unsigned i = tid; i < cnt_g; i += 256) {
        unsigned v = pays[i];
        unsigned pos = atomicAdd(&cur[(v >> 25) & 63u], 1u);
        sorted[pos] = v;
    }
    __syncthreads();

    const unsigned* P32 = reinterpret_cast<const unsigned*>(Pp);
    const unsigned* Q32 = reinterpret_cast<const unsigned*>(Qp);
    for (int si = 0; si < 16; ++si) {
        const int lo = wv * 16 + si;
        const int seg = bkt * SPB + lo;
        const unsigned s0 = offs[lo], s1 = offs[lo + 1];
        unsigned qv = Q32[(size_t)seg * 64 + lane];
        float q0 = uif(qv << 16);
        float q1 = uif(qv & 0xffff0000u);
        float acc0 = 0.f, acc1 = 0.f, wsum = 0.f;
        unsigned scnt = s1 - s0;

        for (unsigned bse = s0; bse < s1; bse += 8) {
            unsigned pv[8]; float wf[8];
#pragma unroll
            for (int k = 0; k < 8; ++k) {
                unsigned idx = bse + (unsigned)k;
                unsigned c = (idx < s1) ? sorted[idx] : 0u;     // wave-uniform broadcast
                wf[k] = (float)((c >> 12) & 8191u) * (1.0f / 8192.0f);
                pv[k] = P32[(size_t)(rowbase + (int)(c & 0xfffu)) * 64 + lane];
            }
#pragma unroll
            for (int k = 0; k < 8; ++k) {
                float p0 = uif(pv[k] << 16);
                float p1 = uif(pv[k] & 0xffff0000u);
                acc0 = fmaf(wf[k], fmaxf(q0 + p0, 0.f), acc0);
                acc1 = fmaf(wf[k], fmaxf(q1 + p1, 0.f), acc1);
                wsum += wf[k];
            }
        }
        if (novf > 0) {                               // normally empty
            unsigned ncl = min(novf, (unsigned)OVFCAP);
            for (unsigned i = 0; i < ncl; ++i) {
                if (ovf_seg[i] == (unsigned)seg) {
                    unsigned c = ovf_pay[i];
                    float w = (float)((c >> 12) & 8191u) * (1.0f / 8192.0f);
                    unsigned pv = P32[(size_t)(rowbase + (int)(c & 0xfffu)) * 64 + lane];
                    acc0 = fmaf(w, fmaxf(q0 + uif(pv << 16), 0.f), acc0);
                    acc1 = fmaf(w, fmaxf(q1 + uif(pv & 0xffff0000u), 0.f), acc1);
                    wsum += w;
                    scnt += 1;
                }
            }
        }
        unsigned sp = (unsigned)f2b(acc0) | ((unsigned)f2b(acc1) << 16);
        *reinterpret_cast<unsigned*>(&S[lo][2 * lane]) = sp;
        if (lane == 0) {
            SW[lo] = wsum;                            // wave-uniform already
            SC[lo] = 1.0f / (float)max(scnt, 1u);
        }
    }
    __syncthreads();

    const int lr = lane & 15, lq = lane >> 4;
#pragma unroll
    for (int rt = 0; rt < 4; ++rt) {
        s16x8 a[4];
#pragma unroll
        for (int ks = 0; ks < 4; ++ks)
            a[ks] = *reinterpret_cast<const s16x8*>(&S[rt * 16 + lr][ks * 32 + lq * 8]);
        f32x4 acc = {0.f, 0.f, 0.f, 0.f};
#pragma unroll
        for (int ks = 0; ks < 4; ++ks) {
            s16x8 bf = *reinterpret_cast<const s16x8*>(&Wm2p[(((wv << 2) + ks) * 64 + lane) * 8]);
            acc = __builtin_amdgcn_mfma_f32_16x16x32_bf16(a[ks], bf, acc, 0, 0, 0);
        }
        float bb = b2[wv * 16 + lr];
#pragma unroll
        for (int j = 0; j < 4; ++j) {
            int r = rt * 16 + lq * 4 + j;
            gathered[(size_t)(bkt * SPB + r) * 64 + wv * 16 + lr] = (acc[j] + SW[r] * bb) * SC[r];
        }
    }
}

// ---------------- node update + legacy fallback ----------------

template<int SCALE>
__launch_bounds__(256, 4)
__global__ void node_kernel(const float* __restrict__ node_feats,
                            const float* __restrict__ sums, const float* __restrict__ counts,
                            const unsigned short* __restrict__ W1p, const float* __restrict__ b1,
                            const unsigned short* __restrict__ W2p, const float* __restrict__ b2,
                            float* __restrict__ out) {
    __shared__ unsigned short A1[64][136];
    __shared__ unsigned short Hs[64][136];
    const int tid = threadIdx.x;
    const int g0 = blockIdx.x * 64;
    for (int i = 0; i < 16; ++i) {
        int idx = i * 256 + tid;
        int node = idx >> 6;
        int p = idx & 63;
        int g = g0 + node;
        float2 v;
        if (p < 32) {
            v = *reinterpret_cast<const float2*>(node_feats + (size_t)g * DNF + 2 * p);
        } else {
            float2 s = *reinterpret_cast<const float2*>(sums + (size_t)g * DM + 2 * p - 64);
            if (SCALE) {
                float scale = 1.0f / fmaxf(counts[g], 1.0f);
                s.x *= scale; s.y *= scale;
            }
            v = s;
        }
        unsigned packed = (unsigned)f2b(v.x) | ((unsigned)f2b(v.y) << 16);
        *reinterpret_cast<unsigned*>(&A1[node][2 * p]) = packed;
    }
    __syncthreads();
    const int wave = tid >> 6, lane = tid & 63;
    const int lr = lane & 15, lq = lane >> 4;
    const int arow = wave * 16 + lr;
    s16x8 a[4];
#pragma unroll
    for (int ks = 0; ks < 4; ++ks)
        a[ks] = *reinterpret_cast<const s16x8*>(&A1[arow][ks * 32 + lq * 8]);
#pragma unroll
    for (int nt = 0; nt < 8; ++nt) {
        f32x4 acc = {0.f, 0.f, 0.f, 0.f};
#pragma unroll
        for (int ks = 0; ks < 4; ++ks) {
            s16x8 bf = *reinterpret_cast<const s16x8*>(&W1p[(((nt << 2) + ks) * 64 + lane) * 8]);
            acc = __builtin_amdgcn_mfma_f32_16x16x32_bf16(a[ks], bf, acc, 0, 0, 0);
        }
        float bias = b1[nt * 16 + lr];
#pragma unroll
        for (int j = 0; j < 4; ++j) {
            float h = acc[j] + bias;
            h = h > 0.f ? h : 0.f;
            Hs[wave * 16 + lq * 4 + j][nt * 16 + lr] = f2b(h);
        }
    }
    s16x8 a2[4];
#pragma unroll
    for (int ks = 0; ks < 4; ++ks)
        a2[ks] = *reinterpret_cast<const s16x8*>(&Hs[arow][ks * 32 + lq * 8]);
#pragma unroll
    for (int nt = 0; nt < 4; ++nt) {
        f32x4 acc = {0.f, 0.f, 0.f, 0.f};
#pragma unroll
        for (int ks = 0; ks < 4; ++ks) {
            s16x8 bf = *reinterpret_cast<const s16x8*>(&W2p[(((nt << 2) + ks) * 64 + lane) * 8]);
            acc = __builtin_amdgcn_mfma_f32_16x16x32_bf16(a2[ks], bf, acc, 0, 0, 0);
        }
        float bias = b2[nt * 16 + lr];
#pragma unroll
        for (int j = 0; j < 4; ++j) {
            int g = g0 + wave * 16 + lq * 4 + j;
            out[(size_t)g * FF + nt * 16 + lr] = acc[j] + bias;
        }
    }
}

__launch_bounds__(256, 4)
__global__ void edge_kernel(const float* __restrict__ node_feats,
                            const int* __restrict__ eb, const int* __restrict__ esrc,
                            const int* __restrict__ edst, const float* __restrict__ evals,
                            const unsigned short* __restrict__ W1p, const float* __restrict__ b1,
                            const unsigned short* __restrict__ W2p, const float* __restrict__ b2,
                            float* __restrict__ sums, float* __restrict__ counts) {
    __shared__ unsigned short A1[64][136];
    __shared__ unsigned short Hs[64][136];
    const int tid = threadIdx.x;
    const int e0 = blockIdx.x * 64;
    if (tid < 64) {
        int e = e0 + tid;
        atomicAdd(&counts[eb[e] * NN + esrc[e]], 1.0f);
    }
    for (int i = 0; i < 16; ++i) {
        int idx = i * 256 + tid;
        int edge = idx >> 6;
        int p = idx & 63;
        int e = e0 + edge;
        int b = eb[e];
        const float* row;
        if (p < 32) row = node_feats + ((size_t)b * NN + esrc[e]) * DNF;
        else        row = node_feats + ((size_t)b * NN + edst[e]) * DNF - 64;
        float2 v = *reinterpret_cast<const float2*>(row + 2 * p);
        unsigned packed = (unsigned)f2b(v.x) | ((unsigned)f2b(v.y) << 16);
        *reinterpret_cast<unsigned*>(&A1[edge][2 * p]) = packed;
    }
    __syncthreads();
    const int wave = tid >> 6, lane = tid & 63;
    const int lr = lane & 15, lq = lane >> 4;
    const int arow = wave * 16 + lr;
    s16x8 a[4];
#pragma unroll
    for (int ks = 0; ks < 4; ++ks)
        a[ks] = *reinterpret_cast<const s16x8*>(&A1[arow][ks * 32 + lq * 8]);
#pragma unroll
    for (int nt = 0; nt < 8; ++nt) {
        f32x4 acc = {0.f, 0.f, 0.f, 0.f};
#pragma unroll
        for (int ks = 0; ks < 4; ++ks) {
            s16x8 bf = *reinterpret_cast<const s16x8*>(&W1p[(((nt << 2) + ks) * 64 + lane) * 8]);
            acc = __builtin_amdgcn_mfma_f32_16x16x32_bf16(a[ks], bf, acc, 0, 0, 0);
        }
        float bias = b1[nt * 16 + lr];
#pragma unroll
        for (int j = 0; j < 4; ++j) {
            float h = acc[j] + bias;
            h = h > 0.f ? h : 0.f;
            Hs[wave * 16 + lq * 4 + j][nt * 16 + lr] = f2b(h);
        }
    }
    s16x8 a2[4];
#pragma unroll
    for (int ks = 0; ks < 4; ++ks)
        a2[ks] = *reinterpret_cast<const s16x8*>(&Hs[arow][ks * 32 + lq * 8]);
    float ev[4]; int seg4[4];
#pragma unroll
    for (int j = 0; j < 4; ++j) {
        int r = e0 + wave * 16 + lq * 4 + j;
        ev[j] = evals[r];
        seg4[j] = eb[r] * NN + esrc[r];
    }
#pragma unroll
    for (int nt = 0; nt < 4; ++nt) {
        f32x4 acc = {0.f, 0.f, 0.f, 0.f};
#pragma unroll
        for (int ks = 0; ks < 4; ++ks) {
            s16x8 bf = *reinterpret_cast<const s16x8*>(&W2p[(((nt << 2) + ks) * 64 + lane) * 8]);
            acc = __builtin_amdgcn_mfma_f32_16x16x32_bf16(a2[ks], bf, acc, 0, 0, 0);
        }
        float bias = b2[nt * 16 + lr];
#pragma unroll
        for (int j = 0; j < 4; ++j) {
            float m = (acc[j] + bias) * ev[j];
            atomicAdd(&sums[(size_t)seg4[j] * DM + nt * 16 + lr], m);
        }
    }
}

extern "C" void kernel_launch(void* const* d_in, const int* in_sizes, int n_in,
                              void* d_out, int out_size, void* d_ws, size_t ws_size,
                              hipStream_t stream) {
    const float* node_feats = (const float*)d_in[0];
    const int*   eb    = (const int*)d_in[1];
    const int*   esrc  = (const int*)d_in[2];
    const int*   edst  = (const int*)d_in[3];
    const float* evals = (const float*)d_in[4];
    const float* Wm1 = (const float*)d_in[5];
    const float* bm1 = (const float*)d_in[6];
    const float* Wm2 = (const float*)d_in[7];
    const float* bm2 = (const float*)d_in[8];
    const float* Wu1 = (const float*)d_in[9];
    const float* bu1 = (const float*)d_in[10];
    const float* Wu2 = (const float*)d_in[11];
    const float* bu2 = (const float*)d_in[12];
    float* out = (float*)d_out;
    char* ws = (char*)d_ws;

    const size_t NEED = 24742016;
    if (ws_size >= NEED) {
        unsigned short* Qp      = (unsigned short*)(ws);              // 8 MB
        unsigned short* Pp      = (unsigned short*)(ws + 8388608);    // 8 MB
        unsigned*       payslot = (unsigned*)(ws + 16777216);         // 512*3584*4 = 7,340,032
        unsigned*       gcur    = (unsigned*)(ws + 24117248);         // 2048 B
        unsigned*       ovf_cnt = (unsigned*)(ws + 24119296);         // 128 B
        unsigned*       ovf_seg = (unsigned*)(ws + 24119424);         // 256 KB
        unsigned*       ovf_pay = (unsigned*)(ws + 24381568);         // 256 KB
        unsigned short* Qw      = (unsigned short*)(ws + 24643712);   // 16 KB
        unsigned short* Pw      = (unsigned short*)(ws + 24660096);   // 16 KB
        unsigned short* Wu1p    = (unsigned short*)(ws + 24676480);   // 32 KB
        unsigned short* Wu2p    = (unsigned short*)(ws + 24709248);   // 16 KB
        unsigned short* Wm2p    = (unsigned short*)(ws + 24725632);   // 16 KB

        hipMemsetAsync(gcur, 0, 2048 + 128, stream);  // gcur + ovf_cnt contiguous
        pack_all<<<192, 256, 0, stream>>>(Wm1, Wm2, Wu1, Wu2, Qw, Pw, Wm2p, Wu1p, Wu2p);
        precompute_pq<<<512, 256, 0, stream>>>(node_feats, Qw, Pw, bm1, Qp, Pp);
        bucket_scatter<<<NEDGE / EPB, 256, 0, stream>>>(eb, esrc, edst, evals,
                                                        gcur, payslot, ovf_cnt, ovf_seg, ovf_pay);
        bucket_segment<<<NBKT, 256, 0, stream>>>(Qp, Pp, payslot, gcur,
                                                 ovf_cnt, ovf_seg, ovf_pay, Wm2p, bm2, out);
        node_kernel<0><<<(NB * NN) / 64, 256, 0, stream>>>(node_feats, out, nullptr,
                                                           Wu1p, bu1, Wu2p, bu2, out);
    } else {
        float* counts          = (float*)ws;
        unsigned short* W1p    = (unsigned short*)(ws + 131072);
        unsigned short* W2p    = (unsigned short*)(ws + 163840);
        unsigned short* Wu1p   = (unsigned short*)(ws + 180224);
        unsigned short* Wu2p   = (unsigned short*)(ws + 212992);
        hipMemsetAsync(d_out, 0, (size_t)out_size * sizeof(float), stream);
        hipMemsetAsync(counts, 0, 32768 * sizeof(float), stream);
        pack_weights<<<64, 256, 0, stream>>>(Wm1, W1p, 128, 128);
        pack_weights<<<32, 256, 0, stream>>>(Wm2, W2p, 128, 64);
        pack_weights<<<64, 256, 0, stream>>>(Wu1, Wu1p, 128, 128);
        pack_weights<<<32, 256, 0, stream>>>(Wu2, Wu2p, 128, 64);
        edge_kernel<<<NEDGE / 64, 256, 0, stream>>>(node_feats, eb, esrc, edst, evals,
                                                    W1p, bm1, W2p, bm2, out, counts);
        node_kernel<1><<<(NB * NN) / 64, 256, 0, stream>>>(node_feats, out, counts,
                                                           Wu1p, bu1, Wu2p, bu2, out);
    }
}

// Round 6
// 120.183 us; speedup vs baseline: 1.2312x; 1.2312x over previous
//
#include <hip/hip_runtime.h>

#define NB 8
#define NN 4096
#define DNF 64
#define NEDGE 1048576
#define DM 64
#define FF 64

#define NBKT2 2048        // buckets (seg>>4)
#define SPB2 16           // segments per bucket
#define REGCAP 768        // slots per bucket (mean 512, +11 sigma) + ovf list
#define OVFCAP 65536

using f32x4 = __attribute__((ext_vector_type(4))) float;
using s16x8 = __attribute__((ext_vector_type(8))) short;

__device__ __forceinline__ unsigned short f2b(float f) {
    union { float f; unsigned u; } v; v.f = f;
    unsigned r = (v.u + 0x7fffu + ((v.u >> 16) & 1u)) >> 16;
    return (unsigned short)r;
}
__device__ __forceinline__ float uif(unsigned u) {
    union { unsigned u; float f; } v; v.u = u;
    return v.f;
}

// Pack W [K x Ncols] (f32 row-major) into MFMA B-fragment order (bf16)
__device__ __forceinline__ void pack_one(const float* __restrict__ W,
                                         unsigned short* __restrict__ out,
                                         int K, int Ncols, int idx) {
    int j = idx & 7;
    int lane = (idx >> 3) & 63;
    int frag = idx >> 9;
    int KS = K >> 5;
    int ks = frag % KS;
    int nt = frag / KS;
    int k = ks * 32 + ((lane >> 4) << 3) + j;
    int col = nt * 16 + (lane & 15);
    out[idx] = f2b(W[k * Ncols + col]);
}

__global__ void pack_all(const float* __restrict__ Wm1, const float* __restrict__ Wm2,
                         const float* __restrict__ Wu1, const float* __restrict__ Wu2,
                         unsigned short* __restrict__ Qw, unsigned short* __restrict__ Pw,
                         unsigned short* __restrict__ Wm2p,
                         unsigned short* __restrict__ Wu1p, unsigned short* __restrict__ Wu2p) {
    int idx = blockIdx.x * 256 + threadIdx.x;
    if (idx < 8192)        pack_one(Wm1,              Qw,   64, 128, idx);
    else if (idx < 16384)  pack_one(Wm1 + 64 * 128,   Pw,   64, 128, idx - 8192);
    else if (idx < 24576)  pack_one(Wm2,              Wm2p, 128, 64, idx - 16384);
    else if (idx < 40960)  pack_one(Wu1,              Wu1p, 128, 128, idx - 24576);
    else                   pack_one(Wu2,              Wu2p, 128, 64, idx - 40960);
}

__global__ void pack_weights(const float* __restrict__ W, unsigned short* __restrict__ out,
                             int K, int Ncols) {
    int idx = blockIdx.x * 256 + threadIdx.x;
    if (idx >= K * Ncols) return;
    pack_one(W, out, K, Ncols, idx);
}

// Q = X @ Wm1[0:64,:] + b1 (bias folded), P = X @ Wm1[64:128,:]  (bf16, 32768 x 128)
__launch_bounds__(256, 4)
__global__ void precompute_pq(const float* __restrict__ X,
                              const unsigned short* __restrict__ Qw,
                              const unsigned short* __restrict__ Pw,
                              const float* __restrict__ b1,
                              unsigned short* __restrict__ Qp,
                              unsigned short* __restrict__ Pp) {
    __shared__ unsigned short A[64][72];
    const int tid = threadIdx.x;
    const int g0 = blockIdx.x * 64;
    for (int i = 0; i < 16; ++i) {
        int idx = i * 256 + tid;
        int node = idx >> 6;
        int f = idx & 63;
        A[node][f] = f2b(X[(size_t)(g0 + node) * DNF + f]);
    }
    __syncthreads();
    const int wave = tid >> 6, lane = tid & 63;
    const int lr = lane & 15, lq = lane >> 4;
    const int arow = wave * 16 + lr;
    s16x8 a[2];
#pragma unroll
    for (int ks = 0; ks < 2; ++ks)
        a[ks] = *reinterpret_cast<const s16x8*>(&A[arow][ks * 32 + lq * 8]);
#pragma unroll
    for (int nt = 0; nt < 8; ++nt) {
        f32x4 accQ = {0.f, 0.f, 0.f, 0.f};
        f32x4 accP = {0.f, 0.f, 0.f, 0.f};
#pragma unroll
        for (int ks = 0; ks < 2; ++ks) {
            s16x8 bq = *reinterpret_cast<const s16x8*>(&Qw[(((nt << 1) + ks) * 64 + lane) * 8]);
            s16x8 bp = *reinterpret_cast<const s16x8*>(&Pw[(((nt << 1) + ks) * 64 + lane) * 8]);
            accQ = __builtin_amdgcn_mfma_f32_16x16x32_bf16(a[ks], bq, accQ, 0, 0, 0);
            accP = __builtin_amdgcn_mfma_f32_16x16x32_bf16(a[ks], bp, accP, 0, 0, 0);
        }
        int col = nt * 16 + lr;
        float bias = b1[col];
#pragma unroll
        for (int j = 0; j < 4; ++j) {
            int row = g0 + wave * 16 + lq * 4 + j;
            Qp[(size_t)row * 128 + col] = f2b(accQ[j] + bias);
            Pp[(size_t)row * 128 + col] = f2b(accP[j]);
        }
    }
}

// Pass A: per-edge append into per-bucket region. Counters line-padded (128B).
// Frontier = 2048 buckets x 64B = 128KB -> L2-resident, appends coalesce in L2.
// payload = dst[0:12) | w13[12:25) | seg_lo4[25:29)
__launch_bounds__(256, 8)
__global__ void scatter16(const int* __restrict__ eb, const int* __restrict__ esrc,
                          const int* __restrict__ edst, const float* __restrict__ evals,
                          unsigned* __restrict__ gcur, unsigned* __restrict__ payslot,
                          unsigned* __restrict__ ovf_cnt, unsigned* __restrict__ ovf_seg,
                          unsigned* __restrict__ ovf_pay) {
    const int t0 = blockIdx.x * 512 + threadIdx.x;
#pragma unroll
    for (int k = 0; k < 2; ++k) {
        int e = t0 + k * 256;
        int seg = eb[e] * NN + esrc[e];
        unsigned wq = (unsigned)fminf(evals[e] * 8192.0f + 0.5f, 8191.0f);
        unsigned pay = (unsigned)edst[e] | (wq << 12) | ((unsigned)(seg & 15) << 25);
        int bkt = seg >> 4;
        unsigned pos = atomicAdd(&gcur[bkt * 32], 1u);
        if (pos < (unsigned)REGCAP) {
            payslot[(size_t)bkt * REGCAP + pos] = pay;
        } else {
            unsigned o = atomicAdd(ovf_cnt, 1u);
            if (o < (unsigned)OVFCAP) { ovf_seg[o] = (unsigned)seg; ovf_pay[o] = pay; }
        }
    }
}

// Pass B: one bucket (16 segments = 16 consecutive nodes) per block.
// 16-bin LDS counting sort -> per-segment reduce s = sum w*relu(Q+P) ->
// MFMA gathered = (S@Wm2 + sumw*b2)/cnt -> FUSED node MLP -> out.
__launch_bounds__(256, 6)
__global__ void bucket16_fused(const unsigned short* __restrict__ Qp,
                               const unsigned short* __restrict__ Pp,
                               const unsigned* __restrict__ payslot,
                               const unsigned* __restrict__ gcur,
                               const unsigned* __restrict__ ovf_cnt,
                               const unsigned* __restrict__ ovf_seg,
                               const unsigned* __restrict__ ovf_pay,
                               const unsigned short* __restrict__ Wm2p,
                               const float* __restrict__ b2m,
                               const float* __restrict__ X,
                               const unsigned short* __restrict__ Wu1p,
                               const float* __restrict__ bu1,
                               const unsigned short* __restrict__ Wu2p,
                               const float* __restrict__ bu2,
                               float* __restrict__ out) {
    __shared__ unsigned sorted[REGCAP];
    __shared__ unsigned short S[16][136];
    __shared__ unsigned short A1[16][136];
    __shared__ unsigned short Hs[16][136];
    __shared__ unsigned h[16];
    __shared__ unsigned offs[17];
    __shared__ unsigned curb[16];
    __shared__ float SW[16], SC[16];
    const int tid = threadIdx.x, wv = tid >> 6, lane = tid & 63;
    const int bkt = blockIdx.x;
    const int node0 = bkt * SPB2;                 // first seg == first node id
    const int rowbase = (bkt >> 8) << 12;         // batch * NN
    const unsigned cnt = min(gcur[bkt * 32], (unsigned)REGCAP);
    const unsigned novf = ovf_cnt[0];

    // stage node feats into A1[:, 0:64]
#pragma unroll
    for (int i = 0; i < 4; ++i) {
        int idx = i * 256 + tid;
        int row = idx >> 6, f = idx & 63;
        A1[row][f] = f2b(X[(size_t)(node0 + row) * DNF + f]);
    }
    if (tid < 16) h[tid] = 0;
    __syncthreads();
    for (unsigned i = tid; i < cnt; i += 256) {
        unsigned v = payslot[(size_t)bkt * REGCAP + i];
        atomicAdd(&h[(v >> 25) & 15u], 1u);
    }
    __syncthreads();
    if (tid < 16) {                                // wave-0 inclusive scan of 16 bins
        int x = (int)h[tid];
#pragma unroll
        for (int o = 1; o < 16; o <<= 1) {
            int y = __shfl_up(x, o);
            if (tid >= o) x += y;
        }
        offs[tid + 1] = (unsigned)x;
        if (tid == 0) offs[0] = 0;
    }
    __syncthreads();
    if (tid < 16) curb[tid] = offs[tid];
    __syncthreads();
    for (unsigned i = tid; i < cnt; i += 256) {
        unsigned v = payslot[(size_t)bkt * REGCAP + i];
        unsigned pos = atomicAdd(&curb[(v >> 25) & 15u], 1u);
        sorted[pos] = v;
    }
    __syncthreads();

    const unsigned* P32 = reinterpret_cast<const unsigned*>(Pp);
    const unsigned* Q32 = reinterpret_cast<const unsigned*>(Qp);
    for (int si = 0; si < 4; ++si) {
        const int lo = wv * 4 + si;
        const int seg = node0 + lo;
        const unsigned s0 = offs[lo], s1 = offs[lo + 1];
        unsigned qv = Q32[(size_t)seg * 64 + lane];
        float q0 = uif(qv << 16);
        float q1 = uif(qv & 0xffff0000u);
        float acc0 = 0.f, acc1 = 0.f, wsum = 0.f;
        unsigned scnt = s1 - s0;

        for (unsigned bse = s0; bse < s1; bse += 8) {
            unsigned pv[8]; float wf[8];
#pragma unroll
            for (int k = 0; k < 8; ++k) {
                unsigned idx = bse + (unsigned)k;
                unsigned c = (idx < s1) ? sorted[idx] : 0u;   // wave-uniform broadcast
                wf[k] = (float)((c >> 12) & 8191u) * (1.0f / 8192.0f);
                pv[k] = P32[(size_t)(rowbase + (int)(c & 0xfffu)) * 64 + lane];
            }
#pragma unroll
            for (int k = 0; k < 8; ++k) {
                float p0 = uif(pv[k] << 16);
                float p1 = uif(pv[k] & 0xffff0000u);
                acc0 = fmaf(wf[k], fmaxf(q0 + p0, 0.f), acc0);
                acc1 = fmaf(wf[k], fmaxf(q1 + p1, 0.f), acc1);
                wsum += wf[k];
            }
        }
        if (novf > 0) {                            // normally empty, guaranteed-correct
            unsigned ncl = min(novf, (unsigned)OVFCAP);
            for (unsigned i = 0; i < ncl; ++i) {
                if (ovf_seg[i] == (unsigned)seg) {
                    unsigned c = ovf_pay[i];
                    float w = (float)((c >> 12) & 8191u) * (1.0f / 8192.0f);
                    unsigned pv = P32[(size_t)(rowbase + (int)(c & 0xfffu)) * 64 + lane];
                    acc0 = fmaf(w, fmaxf(q0 + uif(pv << 16), 0.f), acc0);
                    acc1 = fmaf(w, fmaxf(q1 + uif(pv & 0xffff0000u), 0.f), acc1);
                    wsum += w;
                    scnt += 1;
                }
            }
        }
        unsigned sp = (unsigned)f2b(acc0) | ((unsigned)f2b(acc1) << 16);
        *reinterpret_cast<unsigned*>(&S[lo][2 * lane]) = sp;
        if (lane == 0) {
            SW[lo] = wsum;
            SC[lo] = 1.0f / (float)max(scnt, 1u);
        }
    }
    __syncthreads();

    const int lr = lane & 15, lq = lane >> 4;
    // gathered = (S @ Wm2 + sumw*b2)/cnt -> A1[:, 64:128] (bf16)
    {
        s16x8 a[4];
#pragma unroll
        for (int ks = 0; ks < 4; ++ks)
            a[ks] = *reinterpret_cast<const s16x8*>(&S[lr][ks * 32 + lq * 8]);
        f32x4 acc = {0.f, 0.f, 0.f, 0.f};
#pragma unroll
        for (int ks = 0; ks < 4; ++ks) {
            s16x8 bf = *reinterpret_cast<const s16x8*>(&Wm2p[(((wv << 2) + ks) * 64 + lane) * 8]);
            acc = __builtin_amdgcn_mfma_f32_16x16x32_bf16(a[ks], bf, acc, 0, 0, 0);
        }
        float bb = b2m[wv * 16 + lr];
#pragma unroll
        for (int j = 0; j < 4; ++j) {
            int r = lq * 4 + j;
            float g = (acc[j] + SW[r] * bb) * SC[r];
            A1[r][64 + wv * 16 + lr] = f2b(g);
        }
    }
    __syncthreads();

    // node MLP layer 1: relu([X|gathered] @ Wu1 + bu1) -> Hs
    {
        s16x8 a1[4];
#pragma unroll
        for (int ks = 0; ks < 4; ++ks)
            a1[ks] = *reinterpret_cast<const s16x8*>(&A1[lr][ks * 32 + lq * 8]);
#pragma unroll
        for (int t = 0; t < 2; ++t) {
            int nt = wv * 2 + t;
            f32x4 acc = {0.f, 0.f, 0.f, 0.f};
#pragma unroll
            for (int ks = 0; ks < 4; ++ks) {
                s16x8 bf = *reinterpret_cast<const s16x8*>(&Wu1p[(((nt << 2) + ks) * 64 + lane) * 8]);
                acc = __builtin_amdgcn_mfma_f32_16x16x32_bf16(a1[ks], bf, acc, 0, 0, 0);
            }
            float bias = bu1[nt * 16 + lr];
#pragma unroll
            for (int j = 0; j < 4; ++j) {
                float hh = fmaxf(acc[j] + bias, 0.f);
                Hs[lq * 4 + j][nt * 16 + lr] = f2b(hh);
            }
        }
    }
    __syncthreads();

    // layer 2: Hs @ Wu2 + bu2 -> out
    {
        s16x8 a2[4];
#pragma unroll
        for (int ks = 0; ks < 4; ++ks)
            a2[ks] = *reinterpret_cast<const s16x8*>(&Hs[lr][ks * 32 + lq * 8]);
        f32x4 acc = {0.f, 0.f, 0.f, 0.f};
#pragma unroll
        for (int ks = 0; ks < 4; ++ks) {
            s16x8 bf = *reinterpret_cast<const s16x8*>(&Wu2p[(((wv << 2) + ks) * 64 + lane) * 8]);
            acc = __builtin_amdgcn_mfma_f32_16x16x32_bf16(a2[ks], bf, acc, 0, 0, 0);
        }
        float bias = bu2[wv * 16 + lr];
#pragma unroll
        for (int j = 0; j < 4; ++j)
            out[(size_t)(node0 + lq * 4 + j) * FF + wv * 16 + lr] = acc[j] + bias;
    }
}

// ---------------- legacy fallback (small ws) ----------------

template<int SCALE>
__launch_bounds__(256, 4)
__global__ void node_kernel(const float* __restrict__ node_feats,
                            const float* __restrict__ sums, const float* __restrict__ counts,
                            const unsigned short* __restrict__ W1p, const float* __restrict__ b1,
                            const unsigned short* __restrict__ W2p, const float* __restrict__ b2,
                            float* __restrict__ out) {
    __shared__ unsigned short A1[64][136];
    __shared__ unsigned short Hs[64][136];
    const int tid = threadIdx.x;
    const int g0 = blockIdx.x * 64;
    for (int i = 0; i < 16; ++i) {
        int idx = i * 256 + tid;
        int node = idx >> 6;
        int p = idx & 63;
        int g = g0 + node;
        float2 v;
        if (p < 32) {
            v = *reinterpret_cast<const float2*>(node_feats + (size_t)g * DNF + 2 * p);
        } else {
            float2 s = *reinterpret_cast<const float2*>(sums + (size_t)g * DM + 2 * p - 64);
            if (SCALE) {
                float scale = 1.0f / fmaxf(counts[g], 1.0f);
                s.x *= scale; s.y *= scale;
            }
            v = s;
        }
        unsigned packed = (unsigned)f2b(v.x) | ((unsigned)f2b(v.y) << 16);
        *reinterpret_cast<unsigned*>(&A1[node][2 * p]) = packed;
    }
    __syncthreads();
    const int wave = tid >> 6, lane = tid & 63;
    const int lr = lane & 15, lq = lane >> 4;
    const int arow = wave * 16 + lr;
    s16x8 a[4];
#pragma unroll
    for (int ks = 0; ks < 4; ++ks)
        a[ks] = *reinterpret_cast<const s16x8*>(&A1[arow][ks * 32 + lq * 8]);
#pragma unroll
    for (int nt = 0; nt < 8; ++nt) {
        f32x4 acc = {0.f, 0.f, 0.f, 0.f};
#pragma unroll
        for (int ks = 0; ks < 4; ++ks) {
            s16x8 bf = *reinterpret_cast<const s16x8*>(&W1p[(((nt << 2) + ks) * 64 + lane) * 8]);
            acc = __builtin_amdgcn_mfma_f32_16x16x32_bf16(a[ks], bf, acc, 0, 0, 0);
        }
        float bias = b1[nt * 16 + lr];
#pragma unroll
        for (int j = 0; j < 4; ++j) {
            float h = acc[j] + bias;
            h = h > 0.f ? h : 0.f;
            Hs[wave * 16 + lq * 4 + j][nt * 16 + lr] = f2b(h);
        }
    }
    s16x8 a2[4];
#pragma unroll
    for (int ks = 0; ks < 4; ++ks)
        a2[ks] = *reinterpret_cast<const s16x8*>(&Hs[arow][ks * 32 + lq * 8]);
#pragma unroll
    for (int nt = 0; nt < 4; ++nt) {
        f32x4 acc = {0.f, 0.f, 0.f, 0.f};
#pragma unroll
        for (int ks = 0; ks < 4; ++ks) {
            s16x8 bf = *reinterpret_cast<const s16x8*>(&W2p[(((nt << 2) + ks) * 64 + lane) * 8]);
            acc = __builtin_amdgcn_mfma_f32_16x16x32_bf16(a2[ks], bf, acc, 0, 0, 0);
        }
        float bias = b2[nt * 16 + lr];
#pragma unroll
        for (int j = 0; j < 4; ++j) {
            int g = g0 + wave * 16 + lq * 4 + j;
            out[(size_t)g * FF + nt * 16 + lr] = acc[j] + bias;
        }
    }
}

__launch_bounds__(256, 4)
__global__ void edge_kernel(const float* __restrict__ node_feats,
                            const int* __restrict__ eb, const int* __restrict__ esrc,
                            const int* __restrict__ edst, const float* __restrict__ evals,
                            const unsigned short* __restrict__ W1p, const float* __restrict__ b1,
                            const unsigned short* __restrict__ W2p, const float* __restrict__ b2,
                            float* __restrict__ sums, float* __restrict__ counts) {
    __shared__ unsigned short A1[64][136];
    __shared__ unsigned short Hs[64][136];
    const int tid = threadIdx.x;
    const int e0 = blockIdx.x * 64;
    if (tid < 64) {
        int e = e0 + tid;
        atomicAdd(&counts[eb[e] * NN + esrc[e]], 1.0f);
    }
    for (int i = 0; i < 16; ++i) {
        int idx = i * 256 + tid;
        int edge = idx >> 6;
        int p = idx & 63;
        int e = e0 + edge;
        int b = eb[e];
        const float* row;
        if (p < 32) row = node_feats + ((size_t)b * NN + esrc[e]) * DNF;
        else        row = node_feats + ((size_t)b * NN + edst[e]) * DNF - 64;
        float2 v = *reinterpret_cast<const float2*>(row + 2 * p);
        unsigned packed = (unsigned)f2b(v.x) | ((unsigned)f2b(v.y) << 16);
        *reinterpret_cast<unsigned*>(&A1[edge][2 * p]) = packed;
    }
    __syncthreads();
    const int wave = tid >> 6, lane = tid & 63;
    const int lr = lane & 15, lq = lane >> 4;
    const int arow = wave * 16 + lr;
    s16x8 a[4];
#pragma unroll
    for (int ks = 0; ks < 4; ++ks)
        a[ks] = *reinterpret_cast<const s16x8*>(&A1[arow][ks * 32 + lq * 8]);
#pragma unroll
    for (int nt = 0; nt < 8; ++nt) {
        f32x4 acc = {0.f, 0.f, 0.f, 0.f};
#pragma unroll
        for (int ks = 0; ks < 4; ++ks) {
            s16x8 bf = *reinterpret_cast<const s16x8*>(&W1p[(((nt << 2) + ks) * 64 + lane) * 8]);
            acc = __builtin_amdgcn_mfma_f32_16x16x32_bf16(a[ks], bf, acc, 0, 0, 0);
        }
        float bias = b1[nt * 16 + lr];
#pragma unroll
        for (int j = 0; j < 4; ++j) {
            float h = acc[j] + bias;
            h = h > 0.f ? h : 0.f;
            Hs[wave * 16 + lq * 4 + j][nt * 16 + lr] = f2b(h);
        }
    }
    s16x8 a2[4];
#pragma unroll
    for (int ks = 0; ks < 4; ++ks)
        a2[ks] = *reinterpret_cast<const s16x8*>(&Hs[arow][ks * 32 + lq * 8]);
    float ev[4]; int seg4[4];
#pragma unroll
    for (int j = 0; j < 4; ++j) {
        int r = e0 + wave * 16 + lq * 4 + j;
        ev[j] = evals[r];
        seg4[j] = eb[r] * NN + esrc[r];
    }
#pragma unroll
    for (int nt = 0; nt < 4; ++nt) {
        f32x4 acc = {0.f, 0.f, 0.f, 0.f};
#pragma unroll
        for (int ks = 0; ks < 4; ++ks) {
            s16x8 bf = *reinterpret_cast<const s16x8*>(&W2p[(((nt << 2) + ks) * 64 + lane) * 8]);
            acc = __builtin_amdgcn_mfma_f32_16x16x32_bf16(a2[ks], bf, acc, 0, 0, 0);
        }
        float bias = b2[nt * 16 + lr];
#pragma unroll
        for (int j = 0; j < 4; ++j) {
            float m = (acc[j] + bias) * ev[j];
            atomicAdd(&sums[(size_t)seg4[j] * DM + nt * 16 + lr], m);
        }
    }
}

extern "C" void kernel_launch(void* const* d_in, const int* in_sizes, int n_in,
                              void* d_out, int out_size, void* d_ws, size_t ws_size,
                              hipStream_t stream) {
    const float* node_feats = (const float*)d_in[0];
    const int*   eb    = (const int*)d_in[1];
    const int*   esrc  = (const int*)d_in[2];
    const int*   edst  = (const int*)d_in[3];
    const float* evals = (const float*)d_in[4];
    const float* Wm1 = (const float*)d_in[5];
    const float* bm1 = (const float*)d_in[6];
    const float* Wm2 = (const float*)d_in[7];
    const float* bm2 = (const float*)d_in[8];
    const float* Wu1 = (const float*)d_in[9];
    const float* bu1 = (const float*)d_in[10];
    const float* Wu2 = (const float*)d_in[11];
    const float* bu2 = (const float*)d_in[12];
    float* out = (float*)d_out;
    char* ws = (char*)d_ws;

    const size_t NEED = 23953536;
    if (ws_size >= NEED) {
        unsigned short* Qp      = (unsigned short*)(ws);              // 8 MB
        unsigned short* Pp      = (unsigned short*)(ws + 8388608);    // 8 MB
        unsigned*       payslot = (unsigned*)(ws + 16777216);         // 2048*768*4 = 6 MB
        unsigned*       gcur    = (unsigned*)(ws + 23068672);         // 2048*128B = 256 KB (padded)
        unsigned*       ovf_cnt = (unsigned*)(ws + 23330816);         // 128 B
        unsigned*       ovf_seg = (unsigned*)(ws + 23330944);         // 256 KB
        unsigned*       ovf_pay = (unsigned*)(ws + 23593088);         // 256 KB
        unsigned short* Qw      = (unsigned short*)(ws + 23855232);   // 16 KB
        unsigned short* Pw      = (unsigned short*)(ws + 23871616);   // 16 KB
        unsigned short* Wu1p    = (unsigned short*)(ws + 23888000);   // 32 KB
        unsigned short* Wu2p    = (unsigned short*)(ws + 23920768);   // 16 KB
        unsigned short* Wm2p    = (unsigned short*)(ws + 23937152);   // 16 KB

        hipMemsetAsync(gcur, 0, 262144 + 128, stream);   // gcur + ovf_cnt contiguous
        pack_all<<<192, 256, 0, stream>>>(Wm1, Wm2, Wu1, Wu2, Qw, Pw, Wm2p, Wu1p, Wu2p);
        precompute_pq<<<512, 256, 0, stream>>>(node_feats, Qw, Pw, bm1, Qp, Pp);
        scatter16<<<NEDGE / 512, 256, 0, stream>>>(eb, esrc, edst, evals,
                                                   gcur, payslot, ovf_cnt, ovf_seg, ovf_pay);
        bucket16_fused<<<NBKT2, 256, 0, stream>>>(Qp, Pp, payslot, gcur,
                                                  ovf_cnt, ovf_seg, ovf_pay,
                                                  Wm2p, bm2, node_feats,
                                                  Wu1p, bu1, Wu2p, bu2, out);
    } else {
        float* counts          = (float*)ws;
        unsigned short* W1p    = (unsigned short*)(ws + 131072);
        unsigned short* W2p    = (unsigned short*)(ws + 163840);
        unsigned short* Wu1p   = (unsigned short*)(ws + 180224);
        unsigned short* Wu2p   = (unsigned short*)(ws + 212992);
        hipMemsetAsync(d_out, 0, (size_t)out_size * sizeof(float), stream);
        hipMemsetAsync(counts, 0, 32768 * sizeof(float), stream);
        pack_weights<<<64, 256, 0, stream>>>(Wm1, W1p, 128, 128);
        pack_weights<<<32, 256, 0, stream>>>(Wm2, W2p, 128, 64);
        pack_weights<<<64, 256, 0, stream>>>(Wu1, Wu1p, 128, 128);
        pack_weights<<<32, 256, 0, stream>>>(Wu2, Wu2p, 128, 64);
        edge_kernel<<<NEDGE / 64, 256, 0, stream>>>(node_feats, eb, esrc, edst, evals,
                                                    W1p, bm1, W2p, bm2, out, counts);
        node_kernel<1><<<(NB * NN) / 64, 256, 0, stream>>>(node_feats, out, counts,
                                                           Wu1p, bu1, Wu2p, bu2, out);
    }
}

// Round 7
// 114.601 us; speedup vs baseline: 1.2912x; 1.0487x over previous
//
#include <hip/hip_runtime.h>

#define NB 8
#define NN 4096
#define DNF 64
#define NEDGE 1048576
#define DM 64
#define FF 64

#define NBKT2 2048        // buckets (seg>>4)
#define SPB2 16           // segments per bucket
#define NXCD 8
#define SUBCAP 192        // slots per (bucket,xcd): mean 64, +17 sigma
#define OVFCAP 65536

using f32x4 = __attribute__((ext_vector_type(4))) float;
using s16x8 = __attribute__((ext_vector_type(8))) short;

__device__ __forceinline__ unsigned short f2b(float f) {
    union { float f; unsigned u; } v; v.f = f;
    unsigned r = (v.u + 0x7fffu + ((v.u >> 16) & 1u)) >> 16;
    return (unsigned short)r;
}
__device__ __forceinline__ float uif(unsigned u) {
    union { unsigned u; float f; } v; v.u = u;
    return v.f;
}

// Pack W [K x Ncols] (f32 row-major) into MFMA B-fragment order (bf16)
__device__ __forceinline__ void pack_one(const float* __restrict__ W,
                                         unsigned short* __restrict__ out,
                                         int K, int Ncols, int idx) {
    int j = idx & 7;
    int lane = (idx >> 3) & 63;
    int frag = idx >> 9;
    int KS = K >> 5;
    int ks = frag % KS;
    int nt = frag / KS;
    int k = ks * 32 + ((lane >> 4) << 3) + j;
    int col = nt * 16 + (lane & 15);
    out[idx] = f2b(W[k * Ncols + col]);
}

__global__ void pack_all(const float* __restrict__ Wm1, const float* __restrict__ Wm2,
                         const float* __restrict__ Wu1, const float* __restrict__ Wu2,
                         unsigned short* __restrict__ Qw, unsigned short* __restrict__ Pw,
                         unsigned short* __restrict__ Wm2p,
                         unsigned short* __restrict__ Wu1p, unsigned short* __restrict__ Wu2p) {
    int idx = blockIdx.x * 256 + threadIdx.x;
    if (idx < 8192)        pack_one(Wm1,              Qw,   64, 128, idx);
    else if (idx < 16384)  pack_one(Wm1 + 64 * 128,   Pw,   64, 128, idx - 8192);
    else if (idx < 24576)  pack_one(Wm2,              Wm2p, 128, 64, idx - 16384);
    else if (idx < 40960)  pack_one(Wu1,              Wu1p, 128, 128, idx - 24576);
    else                   pack_one(Wu2,              Wu2p, 128, 64, idx - 40960);
}

__global__ void pack_weights(const float* __restrict__ W, unsigned short* __restrict__ out,
                             int K, int Ncols) {
    int idx = blockIdx.x * 256 + threadIdx.x;
    if (idx >= K * Ncols) return;
    pack_one(W, out, K, Ncols, idx);
}

// Q = X @ Wm1[0:64,:] + b1 (bias folded), P = X @ Wm1[64:128,:]  (bf16, 32768 x 128)
__launch_bounds__(256, 4)
__global__ void precompute_pq(const float* __restrict__ X,
                              const unsigned short* __restrict__ Qw,
                              const unsigned short* __restrict__ Pw,
                              const float* __restrict__ b1,
                              unsigned short* __restrict__ Qp,
                              unsigned short* __restrict__ Pp) {
    __shared__ unsigned short A[64][72];
    const int tid = threadIdx.x;
    const int g0 = blockIdx.x * 64;
    for (int i = 0; i < 16; ++i) {
        int idx = i * 256 + tid;
        int node = idx >> 6;
        int f = idx & 63;
        A[node][f] = f2b(X[(size_t)(g0 + node) * DNF + f]);
    }
    __syncthreads();
    const int wave = tid >> 6, lane = tid & 63;
    const int lr = lane & 15, lq = lane >> 4;
    const int arow = wave * 16 + lr;
    s16x8 a[2];
#pragma unroll
    for (int ks = 0; ks < 2; ++ks)
        a[ks] = *reinterpret_cast<const s16x8*>(&A[arow][ks * 32 + lq * 8]);
#pragma unroll
    for (int nt = 0; nt < 8; ++nt) {
        f32x4 accQ = {0.f, 0.f, 0.f, 0.f};
        f32x4 accP = {0.f, 0.f, 0.f, 0.f};
#pragma unroll
        for (int ks = 0; ks < 2; ++ks) {
            s16x8 bq = *reinterpret_cast<const s16x8*>(&Qw[(((nt << 1) + ks) * 64 + lane) * 8]);
            s16x8 bp = *reinterpret_cast<const s16x8*>(&Pw[(((nt << 1) + ks) * 64 + lane) * 8]);
            accQ = __builtin_amdgcn_mfma_f32_16x16x32_bf16(a[ks], bq, accQ, 0, 0, 0);
            accP = __builtin_amdgcn_mfma_f32_16x16x32_bf16(a[ks], bp, accP, 0, 0, 0);
        }
        int col = nt * 16 + lr;
        float bias = b1[col];
#pragma unroll
        for (int j = 0; j < 4; ++j) {
            int row = g0 + wave * 16 + lq * 4 + j;
            Qp[(size_t)row * 128 + col] = f2b(accQ[j] + bias);
            Pp[(size_t)row * 128 + col] = f2b(accP[j]);
        }
    }
}

// Pass A: per-edge append into per-(bucket,XCD) sub-list. Lines in payslot are
// written by exactly one XCD -> full-line writebacks (no cross-XCD partial lines).
// payload = dst[0:12) | w13[12:25) | seg_lo4[25:29)
__launch_bounds__(256, 8)
__global__ void scatter_xcd(const int* __restrict__ eb, const int* __restrict__ esrc,
                            const int* __restrict__ edst, const float* __restrict__ evals,
                            unsigned* __restrict__ gcurX, unsigned* __restrict__ payslot,
                            unsigned* __restrict__ ovf_cnt, unsigned* __restrict__ ovf_seg,
                            unsigned* __restrict__ ovf_pay) {
    unsigned xcd;
    asm volatile("s_getreg_b32 %0, hwreg(HW_REG_XCC_ID)" : "=s"(xcd));
    xcd &= (NXCD - 1);
    const int t0 = blockIdx.x * 1024 + threadIdx.x;
    int seg[4]; unsigned pk[4];
#pragma unroll
    for (int k = 0; k < 4; ++k) {
        int e = t0 + k * 256;
        seg[k] = eb[e] * NN + esrc[e];
        unsigned wq = (unsigned)fminf(evals[e] * 8192.0f + 0.5f, 8191.0f);
        pk[k] = (unsigned)edst[e] | (wq << 12) | ((unsigned)(seg[k] & 15) << 25);
    }
    unsigned pos[4];
#pragma unroll
    for (int k = 0; k < 4; ++k)
        pos[k] = atomicAdd(&gcurX[xcd * NBKT2 + (seg[k] >> 4)], 1u);
#pragma unroll
    for (int k = 0; k < 4; ++k) {
        if (pos[k] < (unsigned)SUBCAP) {
            payslot[((size_t)(seg[k] >> 4) * NXCD + xcd) * SUBCAP + pos[k]] = pk[k];
        } else {
            unsigned o = atomicAdd(ovf_cnt, 1u);
            if (o < (unsigned)OVFCAP) { ovf_seg[o] = (unsigned)seg[k]; ovf_pay[o] = pk[k]; }
        }
    }
}

// Pass B: one bucket (16 segments = 16 consecutive nodes) per block.
// Walk 8 per-XCD sub-lists -> 16-bin LDS counting sort -> per-segment reduce
// s = sum w*relu(Q+P) -> MFMA gathered -> FUSED node MLP -> out.
__launch_bounds__(256, 6)
__global__ void bucket16_fused(const unsigned short* __restrict__ Qp,
                               const unsigned short* __restrict__ Pp,
                               const unsigned* __restrict__ payslot,
                               const unsigned* __restrict__ gcurX,
                               const unsigned* __restrict__ ovf_cnt,
                               const unsigned* __restrict__ ovf_seg,
                               const unsigned* __restrict__ ovf_pay,
                               const unsigned short* __restrict__ Wm2p,
                               const float* __restrict__ b2m,
                               const float* __restrict__ X,
                               const unsigned short* __restrict__ Wu1p,
                               const float* __restrict__ bu1,
                               const unsigned short* __restrict__ Wu2p,
                               const float* __restrict__ bu2,
                               float* __restrict__ out) {
    __shared__ unsigned sorted[NXCD * SUBCAP];
    __shared__ unsigned short S[16][136];
    __shared__ unsigned short A1[16][136];
    __shared__ unsigned short Hs[16][136];
    __shared__ unsigned h[16];
    __shared__ unsigned offs[17];
    __shared__ unsigned curb[16];
    __shared__ unsigned cx[NXCD];
    __shared__ float SW[16], SC[16];
    const int tid = threadIdx.x, wv = tid >> 6, lane = tid & 63;
    const int bkt = blockIdx.x;
    const int node0 = bkt * SPB2;                 // first seg == first node id
    const int rowbase = (bkt >> 8) << 12;         // batch * NN
    const unsigned novf = ovf_cnt[0];

    // stage node feats into A1[:, 0:64]
#pragma unroll
    for (int i = 0; i < 4; ++i) {
        int idx = i * 256 + tid;
        int row = idx >> 6, f = idx & 63;
        A1[row][f] = f2b(X[(size_t)(node0 + row) * DNF + f]);
    }
    if (tid < 16) h[tid] = 0;
    if (tid < NXCD) cx[tid] = min(gcurX[tid * NBKT2 + bkt], (unsigned)SUBCAP);
    __syncthreads();
    for (int x = 0; x < NXCD; ++x) {
        unsigned c = cx[x];
        for (unsigned i = tid; i < c; i += 256) {
            unsigned v = payslot[((size_t)bkt * NXCD + x) * SUBCAP + i];
            atomicAdd(&h[(v >> 25) & 15u], 1u);
        }
    }
    __syncthreads();
    if (tid < 16) {                                // wave-0 inclusive scan of 16 bins
        int xx = (int)h[tid];
#pragma unroll
        for (int o = 1; o < 16; o <<= 1) {
            int y = __shfl_up(xx, o);
            if (tid >= o) xx += y;
        }
        offs[tid + 1] = (unsigned)xx;
        if (tid == 0) offs[0] = 0;
    }
    __syncthreads();
    if (tid < 16) curb[tid] = offs[tid];
    __syncthreads();
    for (int x = 0; x < NXCD; ++x) {
        unsigned c = cx[x];
        for (unsigned i = tid; i < c; i += 256) {
            unsigned v = payslot[((size_t)bkt * NXCD + x) * SUBCAP + i];
            unsigned pos = atomicAdd(&curb[(v >> 25) & 15u], 1u);
            sorted[pos] = v;
        }
    }
    __syncthreads();

    const unsigned* P32 = reinterpret_cast<const unsigned*>(Pp);
    const unsigned* Q32 = reinterpret_cast<const unsigned*>(Qp);
    for (int si = 0; si < 4; ++si) {
        const int lo = wv * 4 + si;
        const int seg = node0 + lo;
        const unsigned s0 = offs[lo], s1 = offs[lo + 1];
        unsigned qv = Q32[(size_t)seg * 64 + lane];
        float q0 = uif(qv << 16);
        float q1 = uif(qv & 0xffff0000u);
        float acc0 = 0.f, acc1 = 0.f, wsum = 0.f;
        unsigned scnt = s1 - s0;

        for (unsigned bse = s0; bse < s1; bse += 8) {
            unsigned pv[8]; float wf[8];
#pragma unroll
            for (int k = 0; k < 8; ++k) {
                unsigned idx = bse + (unsigned)k;
                unsigned c = (idx < s1) ? sorted[idx] : 0u;   // wave-uniform broadcast
                wf[k] = (float)((c >> 12) & 8191u) * (1.0f / 8192.0f);
                pv[k] = P32[(size_t)(rowbase + (int)(c & 0xfffu)) * 64 + lane];
            }
#pragma unroll
            for (int k = 0; k < 8; ++k) {
                float p0 = uif(pv[k] << 16);
                float p1 = uif(pv[k] & 0xffff0000u);
                acc0 = fmaf(wf[k], fmaxf(q0 + p0, 0.f), acc0);
                acc1 = fmaf(wf[k], fmaxf(q1 + p1, 0.f), acc1);
                wsum += wf[k];
            }
        }
        if (novf > 0) {                            // normally empty, guaranteed-correct
            unsigned ncl = min(novf, (unsigned)OVFCAP);
            for (unsigned i = 0; i < ncl; ++i) {
                if (ovf_seg[i] == (unsigned)seg) {
                    unsigned c = ovf_pay[i];
                    float w = (float)((c >> 12) & 8191u) * (1.0f / 8192.0f);
                    unsigned pv = P32[(size_t)(rowbase + (int)(c & 0xfffu)) * 64 + lane];
                    acc0 = fmaf(w, fmaxf(q0 + uif(pv << 16), 0.f), acc0);
                    acc1 = fmaf(w, fmaxf(q1 + uif(pv & 0xffff0000u), 0.f), acc1);
                    wsum += w;
                    scnt += 1;
                }
            }
        }
        unsigned sp = (unsigned)f2b(acc0) | ((unsigned)f2b(acc1) << 16);
        *reinterpret_cast<unsigned*>(&S[lo][2 * lane]) = sp;
        if (lane == 0) {
            SW[lo] = wsum;
            SC[lo] = 1.0f / (float)max(scnt, 1u);
        }
    }
    __syncthreads();

    const int lr = lane & 15, lq = lane >> 4;
    // gathered = (S @ Wm2 + sumw*b2)/cnt -> A1[:, 64:128] (bf16)
    {
        s16x8 a[4];
#pragma unroll
        for (int ks = 0; ks < 4; ++ks)
            a[ks] = *reinterpret_cast<const s16x8*>(&S[lr][ks * 32 + lq * 8]);
        f32x4 acc = {0.f, 0.f, 0.f, 0.f};
#pragma unroll
        for (int ks = 0; ks < 4; ++ks) {
            s16x8 bf = *reinterpret_cast<const s16x8*>(&Wm2p[(((wv << 2) + ks) * 64 + lane) * 8]);
            acc = __builtin_amdgcn_mfma_f32_16x16x32_bf16(a[ks], bf, acc, 0, 0, 0);
        }
        float bb = b2m[wv * 16 + lr];
#pragma unroll
        for (int j = 0; j < 4; ++j) {
            int r = lq * 4 + j;
            float g = (acc[j] + SW[r] * bb) * SC[r];
            A1[r][64 + wv * 16 + lr] = f2b(g);
        }
    }
    __syncthreads();

    // node MLP layer 1: relu([X|gathered] @ Wu1 + bu1) -> Hs
    {
        s16x8 a1[4];
#pragma unroll
        for (int ks = 0; ks < 4; ++ks)
            a1[ks] = *reinterpret_cast<const s16x8*>(&A1[lr][ks * 32 + lq * 8]);
#pragma unroll
        for (int t = 0; t < 2; ++t) {
            int nt = wv * 2 + t;
            f32x4 acc = {0.f, 0.f, 0.f, 0.f};
#pragma unroll
            for (int ks = 0; ks < 4; ++ks) {
                s16x8 bf = *reinterpret_cast<const s16x8*>(&Wu1p[(((nt << 2) + ks) * 64 + lane) * 8]);
                acc = __builtin_amdgcn_mfma_f32_16x16x32_bf16(a1[ks], bf, acc, 0, 0, 0);
            }
            float bias = bu1[nt * 16 + lr];
#pragma unroll
            for (int j = 0; j < 4; ++j) {
                float hh = fmaxf(acc[j] + bias, 0.f);
                Hs[lq * 4 + j][nt * 16 + lr] = f2b(hh);
            }
        }
    }
    __syncthreads();

    // layer 2: Hs @ Wu2 + bu2 -> out
    {
        s16x8 a2[4];
#pragma unroll
        for (int ks = 0; ks < 4; ++ks)
            a2[ks] = *reinterpret_cast<const s16x8*>(&Hs[lr][ks * 32 + lq * 8]);
        f32x4 acc = {0.f, 0.f, 0.f, 0.f};
#pragma unroll
        for (int ks = 0; ks < 4; ++ks) {
            s16x8 bf = *reinterpret_cast<const s16x8*>(&Wu2p[(((wv << 2) + ks) * 64 + lane) * 8]);
            acc = __builtin_amdgcn_mfma_f32_16x16x32_bf16(a2[ks], bf, acc, 0, 0, 0);
        }
        float bias = bu2[wv * 16 + lr];
#pragma unroll
        for (int j = 0; j < 4; ++j)
            out[(size_t)(node0 + lq * 4 + j) * FF + wv * 16 + lr] = acc[j] + bias;
    }
}

// ---------------- legacy fallback (small ws) ----------------

template<int SCALE>
__launch_bounds__(256, 4)
__global__ void node_kernel(const float* __restrict__ node_feats,
                            const float* __restrict__ sums, const float* __restrict__ counts,
                            const unsigned short* __restrict__ W1p, const float* __restrict__ b1,
                            const unsigned short* __restrict__ W2p, const float* __restrict__ b2,
                            float* __restrict__ out) {
    __shared__ unsigned short A1[64][136];
    __shared__ unsigned short Hs[64][136];
    const int tid = threadIdx.x;
    const int g0 = blockIdx.x * 64;
    for (int i = 0; i < 16; ++i) {
        int idx = i * 256 + tid;
        int node = idx >> 6;
        int p = idx & 63;
        int g = g0 + node;
        float2 v;
        if (p < 32) {
            v = *reinterpret_cast<const float2*>(node_feats + (size_t)g * DNF + 2 * p);
        } else {
            float2 s = *reinterpret_cast<const float2*>(sums + (size_t)g * DM + 2 * p - 64);
            if (SCALE) {
                float scale = 1.0f / fmaxf(counts[g], 1.0f);
                s.x *= scale; s.y *= scale;
            }
            v = s;
        }
        unsigned packed = (unsigned)f2b(v.x) | ((unsigned)f2b(v.y) << 16);
        *reinterpret_cast<unsigned*>(&A1[node][2 * p]) = packed;
    }
    __syncthreads();
    const int wave = tid >> 6, lane = tid & 63;
    const int lr = lane & 15, lq = lane >> 4;
    const int arow = wave * 16 + lr;
    s16x8 a[4];
#pragma unroll
    for (int ks = 0; ks < 4; ++ks)
        a[ks] = *reinterpret_cast<const s16x8*>(&A1[arow][ks * 32 + lq * 8]);
#pragma unroll
    for (int nt = 0; nt < 8; ++nt) {
        f32x4 acc = {0.f, 0.f, 0.f, 0.f};
#pragma unroll
        for (int ks = 0; ks < 4; ++ks) {
            s16x8 bf = *reinterpret_cast<const s16x8*>(&W1p[(((nt << 2) + ks) * 64 + lane) * 8]);
            acc = __builtin_amdgcn_mfma_f32_16x16x32_bf16(a[ks], bf, acc, 0, 0, 0);
        }
        float bias = b1[nt * 16 + lr];
#pragma unroll
        for (int j = 0; j < 4; ++j) {
            float h = acc[j] + bias;
            h = h > 0.f ? h : 0.f;
            Hs[wave * 16 + lq * 4 + j][nt * 16 + lr] = f2b(h);
        }
    }
    s16x8 a2[4];
#pragma unroll
    for (int ks = 0; ks < 4; ++ks)
        a2[ks] = *reinterpret_cast<const s16x8*>(&Hs[arow][ks * 32 + lq * 8]);
#pragma unroll
    for (int nt = 0; nt < 4; ++nt) {
        f32x4 acc = {0.f, 0.f, 0.f, 0.f};
#pragma unroll
        for (int ks = 0; ks < 4; ++ks) {
            s16x8 bf = *reinterpret_cast<const s16x8*>(&W2p[(((nt << 2) + ks) * 64 + lane) * 8]);
            acc = __builtin_amdgcn_mfma_f32_16x16x32_bf16(a2[ks], bf, acc, 0, 0, 0);
        }
        float bias = b2[nt * 16 + lr];
#pragma unroll
        for (int j = 0; j < 4; ++j) {
            int g = g0 + wave * 16 + lq * 4 + j;
            out[(size_t)g * FF + nt * 16 + lr] = acc[j] + bias;
        }
    }
}

__launch_bounds__(256, 4)
__global__ void edge_kernel(const float* __restrict__ node_feats,
                            const int* __restrict__ eb, const int* __restrict__ esrc,
                            const int* __restrict__ edst, const float* __restrict__ evals,
                            const unsigned short* __restrict__ W1p, const float* __restrict__ b1,
                            const unsigned short* __restrict__ W2p, const float* __restrict__ b2,
                            float* __restrict__ sums, float* __restrict__ counts) {
    __shared__ unsigned short A1[64][136];
    __shared__ unsigned short Hs[64][136];
    const int tid = threadIdx.x;
    const int e0 = blockIdx.x * 64;
    if (tid < 64) {
        int e = e0 + tid;
        atomicAdd(&counts[eb[e] * NN + esrc[e]], 1.0f);
    }
    for (int i = 0; i < 16; ++i) {
        int idx = i * 256 + tid;
        int edge = idx >> 6;
        int p = idx & 63;
        int e = e0 + edge;
        int b = eb[e];
        const float* row;
        if (p < 32) row = node_feats + ((size_t)b * NN + esrc[e]) * DNF;
        else        row = node_feats + ((size_t)b * NN + edst[e]) * DNF - 64;
        float2 v = *reinterpret_cast<const float2*>(row + 2 * p);
        unsigned packed = (unsigned)f2b(v.x) | ((unsigned)f2b(v.y) << 16);
        *reinterpret_cast<unsigned*>(&A1[edge][2 * p]) = packed;
    }
    __syncthreads();
    const int wave = tid >> 6, lane = tid & 63;
    const int lr = lane & 15, lq = lane >> 4;
    const int arow = wave * 16 + lr;
    s16x8 a[4];
#pragma unroll
    for (int ks = 0; ks < 4; ++ks)
        a[ks] = *reinterpret_cast<const s16x8*>(&A1[arow][ks * 32 + lq * 8]);
#pragma unroll
    for (int nt = 0; nt < 8; ++nt) {
        f32x4 acc = {0.f, 0.f, 0.f, 0.f};
#pragma unroll
        for (int ks = 0; ks < 4; ++ks) {
            s16x8 bf = *reinterpret_cast<const s16x8*>(&W1p[(((nt << 2) + ks) * 64 + lane) * 8]);
            acc = __builtin_amdgcn_mfma_f32_16x16x32_bf16(a[ks], bf, acc, 0, 0, 0);
        }
        float bias = b1[nt * 16 + lr];
#pragma unroll
        for (int j = 0; j < 4; ++j) {
            float h = acc[j] + bias;
            h = h > 0.f ? h : 0.f;
            Hs[wave * 16 + lq * 4 + j][nt * 16 + lr] = f2b(h);
        }
    }
    s16x8 a2[4];
#pragma unroll
    for (int ks = 0; ks < 4; ++ks)
        a2[ks] = *reinterpret_cast<const s16x8*>(&Hs[arow][ks * 32 + lq * 8]);
    float ev[4]; int seg4[4];
#pragma unroll
    for (int j = 0; j < 4; ++j) {
        int r = e0 + wave * 16 + lq * 4 + j;
        ev[j] = evals[r];
        seg4[j] = eb[r] * NN + esrc[r];
    }
#pragma unroll
    for (int nt = 0; nt < 4; ++nt) {
        f32x4 acc = {0.f, 0.f, 0.f, 0.f};
#pragma unroll
        for (int ks = 0; ks < 4; ++ks) {
            s16x8 bf = *reinterpret_cast<const s16x8*>(&W2p[(((nt << 2) + ks) * 64 + lane) * 8]);
            acc = __builtin_amdgcn_mfma_f32_16x16x32_bf16(a2[ks], bf, acc, 0, 0, 0);
        }
        float bias = b2[nt * 16 + lr];
#pragma unroll
        for (int j = 0; j < 4; ++j) {
            float m = (acc[j] + bias) * ev[j];
            atomicAdd(&sums[(size_t)seg4[j] * DM + nt * 16 + lr], m);
        }
    }
}

extern "C" void kernel_launch(void* const* d_in, const int* in_sizes, int n_in,
                              void* d_out, int out_size, void* d_ws, size_t ws_size,
                              hipStream_t stream) {
    const float* node_feats = (const float*)d_in[0];
    const int*   eb    = (const int*)d_in[1];
    const int*   esrc  = (const int*)d_in[2];
    const int*   edst  = (const int*)d_in[3];
    const float* evals = (const float*)d_in[4];
    const float* Wm1 = (const float*)d_in[5];
    const float* bm1 = (const float*)d_in[6];
    const float* Wm2 = (const float*)d_in[7];
    const float* bm2 = (const float*)d_in[8];
    const float* Wu1 = (const float*)d_in[9];
    const float* bu1 = (const float*)d_in[10];
    const float* Wu2 = (const float*)d_in[11];
    const float* bu2 = (const float*)d_in[12];
    float* out = (float*)d_out;
    char* ws = (char*)d_ws;

    const size_t NEED = 30048384;
    if (ws_size >= NEED) {
        unsigned short* Qp      = (unsigned short*)(ws);              // 8 MB
        unsigned short* Pp      = (unsigned short*)(ws + 8388608);    // 8 MB
        unsigned*       payslot = (unsigned*)(ws + 16777216);         // 2048*8*192*4 = 12 MB
        unsigned*       gcurX   = (unsigned*)(ws + 29360128);         // 8*2048*4 = 64 KB
        unsigned*       ovf_cnt = (unsigned*)(ws + 29425664);         // 128 B
        unsigned*       ovf_seg = (unsigned*)(ws + 29425792);         // 256 KB
        unsigned*       ovf_pay = (unsigned*)(ws + 29687936);         // 256 KB
        unsigned short* Qw      = (unsigned short*)(ws + 29950080);   // 16 KB
        unsigned short* Pw      = (unsigned short*)(ws + 29966464);   // 16 KB
        unsigned short* Wu1p    = (unsigned short*)(ws + 29982848);   // 32 KB
        unsigned short* Wu2p    = (unsigned short*)(ws + 30015616);   // 16 KB
        unsigned short* Wm2p    = (unsigned short*)(ws + 30032000);   // 16 KB

        hipMemsetAsync(gcurX, 0, 65536 + 128, stream);   // gcurX + ovf_cnt contiguous
        pack_all<<<192, 256, 0, stream>>>(Wm1, Wm2, Wu1, Wu2, Qw, Pw, Wm2p, Wu1p, Wu2p);
        precompute_pq<<<512, 256, 0, stream>>>(node_feats, Qw, Pw, bm1, Qp, Pp);
        scatter_xcd<<<NEDGE / 1024, 256, 0, stream>>>(eb, esrc, edst, evals,
                                                      gcurX, payslot, ovf_cnt, ovf_seg, ovf_pay);
        bucket16_fused<<<NBKT2, 256, 0, stream>>>(Qp, Pp, payslot, gcurX,
                                                  ovf_cnt, ovf_seg, ovf_pay,
                                                  Wm2p, bm2, node_feats,
                                                  Wu1p, bu1, Wu2p, bu2, out);
    } else {
        float* counts          = (float*)ws;
        unsigned short* W1p    = (unsigned short*)(ws + 131072);
        unsigned short* W2p    = (unsigned short*)(ws + 163840);
        unsigned short* Wu1p   = (unsigned short*)(ws + 180224);
        unsigned short* Wu2p   = (unsigned short*)(ws + 212992);
        hipMemsetAsync(d_out, 0, (size_t)out_size * sizeof(float), stream);
        hipMemsetAsync(counts, 0, 32768 * sizeof(float), stream);
        pack_weights<<<64, 256, 0, stream>>>(Wm1, W1p, 128, 128);
        pack_weights<<<32, 256, 0, stream>>>(Wm2, W2p, 128, 64);
        pack_weights<<<64, 256, 0, stream>>>(Wu1, Wu1p, 128, 128);
        pack_weights<<<32, 256, 0, stream>>>(Wu2, Wu2p, 128, 64);
        edge_kernel<<<NEDGE / 64, 256, 0, stream>>>(node_feats, eb, esrc, edst, evals,
                                                    W1p, bm1, W2p, bm2, out, counts);
        node_kernel<1><<<(NB * NN) / 64, 256, 0, stream>>>(node_feats, out, counts,
                                                           Wu1p, bu1, Wu2p, bu2, out);
    }
}